// Round 1
// baseline (1979.346 us; speedup 1.0000x reference)
//
#include <hip/hip_runtime.h>
#include <hip/hip_bf16.h>

#define N_LITS    131072
#define N_CLAUSES 65536
#define N_EDGES   524288
#define FEAT      384
#define F2        768
#define H1        256
#define H2        64

typedef __bf16 bf16_t;
typedef __attribute__((ext_vector_type(8))) __bf16 bf16x8;
typedef __attribute__((ext_vector_type(4))) float f32x4;

// ---- workspace layout (bytes) ----
#define OFF_W1T   0                         // bf16 [256][768]
#define OFF_W2T   (256 * 768 * 2)           // bf16 [64][256]
#define OFF_W3T   (OFF_W2T + 64 * 256 * 2)  // bf16 [32][64] (cols 20..31 zero)
#define OFF_SUMS  (OFF_W3T + 32 * 64 * 2)   // f32 [65536]
#define OFF_CNTS  (OFF_SUMS + 65536 * 4)    // f32 [65536]

// dst[n][k] = bf16(src[k][n]); rows n >= N are zero-padded.
__global__ void k_transpose_bf16(const float* __restrict__ src, bf16_t* __restrict__ dst,
                                 int K, int N, int Npad) {
  int idx = blockIdx.x * blockDim.x + threadIdx.x;
  if (idx >= Npad * K) return;
  int n = idx / K;
  int k = idx - n * K;
  float v = (n < N) ? src[k * N + n] : 0.0f;
  dst[idx] = (bf16_t)v;
}

__global__ __launch_bounds__(256) void k_edge_mlp(
    const float* __restrict__ l_embs, const float* __restrict__ c_embs,
    const int* __restrict__ edge_i, const int* __restrict__ edge_j,
    const bf16_t* __restrict__ W1T, const bf16_t* __restrict__ W2T,
    const bf16_t* __restrict__ W3T,
    const float* __restrict__ b1, const float* __restrict__ b2,
    const float* __restrict__ b3, const float* __restrict__ W4,
    const float* __restrict__ b4,
    float* __restrict__ sums, float* __restrict__ counts)
{
  // per-wave LDS staging; +8 ushort row pad keeps bank conflicts <= ~4-way
  __shared__ __align__(16) bf16_t h1[4][16][264];
  __shared__ __align__(16) bf16_t h2s[4][16][72];

  const int wave = threadIdx.x >> 6;
  const int lane = threadIdx.x & 63;
  const int m    = lane & 15;
  const int quad = lane >> 4;
  const int e0w  = blockIdx.x * 64 + wave * 16;   // first edge of this wave's tile

  // ---- layer 1: C1[16,256] = emb[16,768] @ W1 ----
  // A operand: A[m=lane&15][k=quad*8+j]  (edge row indexed by lane&15)
  const int eA = e0w + m;
  const float* rowL = l_embs + (size_t)edge_i[eA] * FEAT;
  const float* rowC = c_embs + (size_t)edge_j[eA] * FEAT;

  f32x4 acc[16];
#pragma unroll
  for (int nt = 0; nt < 16; ++nt) acc[nt] = (f32x4){0.f, 0.f, 0.f, 0.f};

  for (int s = 0; s < 24; ++s) {
    int k = s * 32 + quad * 8;
    const float* p = (k < FEAT) ? (rowL + k) : (rowC + (k - FEAT));
    float4 v0 = *(const float4*)p;
    float4 v1 = *(const float4*)(p + 4);
    bf16x8 a;
    a[0] = (bf16_t)v0.x; a[1] = (bf16_t)v0.y; a[2] = (bf16_t)v0.z; a[3] = (bf16_t)v0.w;
    a[4] = (bf16_t)v1.x; a[5] = (bf16_t)v1.y; a[6] = (bf16_t)v1.z; a[7] = (bf16_t)v1.w;
    const bf16_t* wb = W1T + (size_t)m * F2 + s * 32 + quad * 8;
#pragma unroll
    for (int nt = 0; nt < 16; ++nt) {
      bf16x8 b = *(const bf16x8*)(wb + nt * 16 * F2);
      acc[nt] = __builtin_amdgcn_mfma_f32_16x16x32_bf16(a, b, acc[nt], 0, 0, 0);
    }
  }

  // D layout: row(edge) = quad*4+r, col = lane&15  -> bias+relu -> LDS (A layout for L2)
#pragma unroll
  for (int nt = 0; nt < 16; ++nt) {
    int col = nt * 16 + m;
    float bb = b1[col];
#pragma unroll
    for (int r = 0; r < 4; ++r) {
      float v = fmaxf(acc[nt][r] + bb, 0.0f);
      h1[wave][quad * 4 + r][col] = (bf16_t)v;
    }
  }
  __syncthreads();

  // ---- layer 2: C2[16,64] = h1[16,256] @ W2 ----
  f32x4 acc2[4];
#pragma unroll
  for (int nt = 0; nt < 4; ++nt) acc2[nt] = (f32x4){0.f, 0.f, 0.f, 0.f};

#pragma unroll
  for (int s = 0; s < 8; ++s) {
    bf16x8 a2 = *(const bf16x8*)&h1[wave][m][s * 32 + quad * 8];
    const bf16_t* wb2 = W2T + (size_t)m * H1 + s * 32 + quad * 8;
#pragma unroll
    for (int nt = 0; nt < 4; ++nt) {
      bf16x8 b = *(const bf16x8*)(wb2 + nt * 16 * H1);
      acc2[nt] = __builtin_amdgcn_mfma_f32_16x16x32_bf16(a2, b, acc2[nt], 0, 0, 0);
    }
  }

#pragma unroll
  for (int nt = 0; nt < 4; ++nt) {
    int col = nt * 16 + m;
    float bb = b2[col];
#pragma unroll
    for (int r = 0; r < 4; ++r) {
      float v = fmaxf(acc2[nt][r] + bb, 0.0f);
      h2s[wave][quad * 4 + r][col] = (bf16_t)v;
    }
  }
  __syncthreads();

  // ---- layer 3: C3[16,32] = h2[16,64] @ W3pad (cols 20..31 are zero) ----
  f32x4 acc3[2];
#pragma unroll
  for (int nt = 0; nt < 2; ++nt) acc3[nt] = (f32x4){0.f, 0.f, 0.f, 0.f};

#pragma unroll
  for (int s = 0; s < 2; ++s) {
    bf16x8 a3 = *(const bf16x8*)&h2s[wave][m][s * 32 + quad * 8];
    const bf16_t* wb3 = W3T + (size_t)m * H2 + s * 32 + quad * 8;
#pragma unroll
    for (int nt = 0; nt < 2; ++nt) {
      bf16x8 b = *(const bf16x8*)(wb3 + nt * 16 * H2);
      acc3[nt] = __builtin_amdgcn_mfma_f32_16x16x32_bf16(a3, b, acc3[nt], 0, 0, 0);
    }
  }

  // ---- layer 4 + per-clause atomics ----
  // my two h3 columns: m (0..15) and m+16 (valid if <20)
  float b3A = b3[m];
  float b3B = (m + 16 < 20) ? b3[m + 16] : 0.0f;
  float w4A = W4[m];                              // m <= 15 < 20, always valid
  float w4B = (m + 16 < 20) ? W4[m + 16] : 0.0f;  // zero weight kills pad cols

  float p[4];
#pragma unroll
  for (int r = 0; r < 4; ++r) {
    float hA = fmaxf(acc3[0][r] + b3A, 0.0f);
    float hB = fmaxf(acc3[1][r] + b3B, 0.0f);
    p[r] = hA * w4A + hB * w4B;
  }
  // reduce over the 16 lanes of each quad (cols of the dot product)
#pragma unroll
  for (int d = 1; d < 16; d <<= 1) {
#pragma unroll
    for (int r = 0; r < 4; ++r) p[r] += __shfl_xor(p[r], d, 64);
  }

  if (m == 0) {
    float bb4 = b4[0];
#pragma unroll
    for (int r = 0; r < 4; ++r) {
      int row = quad * 4 + r;
      int ej = edge_j[e0w + row];
      atomicAdd(&sums[ej], p[r] + bb4);
      atomicAdd(&counts[ej], 1.0f);
    }
  }
}

__global__ void k_means(float* __restrict__ sums, const float* __restrict__ counts) {
  int i = blockIdx.x * blockDim.x + threadIdx.x;
  if (i >= N_CLAUSES) return;
  sums[i] = sums[i] / fmaxf(counts[i], 1.0f);
}

__global__ void k_gather(const float* __restrict__ means, const int* __restrict__ edge_j,
                         float* __restrict__ out) {
  int e = blockIdx.x * blockDim.x + threadIdx.x;
  if (e >= N_EDGES) return;
  out[e] = means[edge_j[e]];
}

extern "C" void kernel_launch(void* const* d_in, const int* in_sizes, int n_in,
                              void* d_out, int out_size, void* d_ws, size_t ws_size,
                              hipStream_t stream) {
  const float* l_embs = (const float*)d_in[0];
  const float* c_embs = (const float*)d_in[1];
  const int*   edge_i = (const int*)d_in[2];
  const int*   edge_j = (const int*)d_in[3];
  const float* W1 = (const float*)d_in[4];
  const float* b1 = (const float*)d_in[5];
  const float* W2 = (const float*)d_in[6];
  const float* b2 = (const float*)d_in[7];
  const float* W3 = (const float*)d_in[8];
  const float* b3 = (const float*)d_in[9];
  const float* W4 = (const float*)d_in[10];
  const float* b4 = (const float*)d_in[11];
  float* out = (float*)d_out;

  char* ws = (char*)d_ws;
  bf16_t* W1T = (bf16_t*)(ws + OFF_W1T);
  bf16_t* W2T = (bf16_t*)(ws + OFF_W2T);
  bf16_t* W3T = (bf16_t*)(ws + OFF_W3T);
  float*  sums   = (float*)(ws + OFF_SUMS);
  float*  counts = (float*)(ws + OFF_CNTS);

  hipMemsetAsync(ws + OFF_SUMS, 0, 2 * N_CLAUSES * 4, stream);

  k_transpose_bf16<<<(256 * 768 + 255) / 256, 256, 0, stream>>>(W1, W1T, 768, 256, 256);
  k_transpose_bf16<<<(64 * 256 + 255) / 256, 256, 0, stream>>>(W2, W2T, 256, 64, 64);
  k_transpose_bf16<<<(32 * 64 + 255) / 256, 256, 0, stream>>>(W3, W3T, 64, 20, 32);

  k_edge_mlp<<<N_EDGES / 64, 256, 0, stream>>>(
      l_embs, c_embs, edge_i, edge_j, W1T, W2T, W3T,
      b1, b2, b3, W4, b4, sums, counts);

  k_means<<<N_CLAUSES / 256, 256, 0, stream>>>(sums, counts);
  k_gather<<<N_EDGES / 256, 256, 0, stream>>>(sums, edge_j, out);
}

// Round 2
// 921.616 us; speedup vs baseline: 2.1477x; 2.1477x over previous
//
#include <hip/hip_runtime.h>
#include <hip/hip_bf16.h>

#define N_LITS    131072
#define N_CLAUSES 65536
#define N_EDGES   524288
#define FEAT      384
#define F2        768
#define H1        256
#define H2        64

typedef __bf16 bf16_t;
typedef __attribute__((ext_vector_type(8))) __bf16 bf16x8;
typedef __attribute__((ext_vector_type(4))) __bf16 bf16x4;
typedef __attribute__((ext_vector_type(4))) float f32x4;

// ---- workspace layout (bytes) ----
#define OFF_W1T   0                         // bf16 [256][768]
#define OFF_W2T   (256 * 768 * 2)           // bf16 [64][256]
#define OFF_W3T   (OFF_W2T + 64 * 256 * 2)  // bf16 [32][64] (rows n>=20 zero)
#define OFF_SUMS  (OFF_W3T + 32 * 64 * 2)   // f32 [65536]
#define OFF_CNTS  (OFF_SUMS + 65536 * 4)    // f32 [65536]

// LDS strides (elements)
#define ASTR 104   // Abuf row stride: 96 + 8 pad  (2-way banks max)
#define H1STR 264  // h1 row stride: 256 + 8 pad
#define H2STR 72   // h2 row stride: 64 + 8 pad

// Fused transpose+cast of W1, W2, W3 (padded to 32 cols).
__global__ void k_prep(const float* __restrict__ W1, const float* __restrict__ W2,
                       const float* __restrict__ W3, bf16_t* __restrict__ W1T,
                       bf16_t* __restrict__ W2T, bf16_t* __restrict__ W3T) {
  int idx = blockIdx.x * blockDim.x + threadIdx.x;
  if (idx < 196608) {
    int n = idx / 768, k = idx - n * 768;
    W1T[idx] = (bf16_t)W1[k * 256 + n];
  } else if (idx < 196608 + 16384) {
    int i = idx - 196608;
    int n = i / 256, k = i - n * 256;
    W2T[i] = (bf16_t)W2[k * 64 + n];
  } else if (idx < 196608 + 16384 + 2048) {
    int i = idx - 196608 - 16384;
    int n = i / 64, k = i - n * 64;
    W3T[i] = (bf16_t)((n < 20) ? W3[k * 20 + n] : 0.0f);
  }
}

__global__ __launch_bounds__(256, 3) void k_edge_mlp(
    const float* __restrict__ l_embs, const float* __restrict__ c_embs,
    const int* __restrict__ edge_i, const int* __restrict__ edge_j,
    const bf16_t* __restrict__ W1T, const bf16_t* __restrict__ W2T,
    const bf16_t* __restrict__ W3T,
    const float* __restrict__ b1, const float* __restrict__ b2,
    const float* __restrict__ b3, const float* __restrict__ W4,
    const float* __restrict__ b4,
    float* __restrict__ sums, float* __restrict__ counts)
{
  // Abuf [64][ASTR] unioned with h2 [64][H2STR]; h1 [64][H1STR] separate.
  __shared__ __align__(16) char smem[64 * ASTR * 2 + 64 * H1STR * 2];
  bf16_t* Abuf = (bf16_t*)smem;                    // layer-1 A staging
  bf16_t* h2s  = (bf16_t*)smem;                    // reused after layer 1
  bf16_t* h1   = (bf16_t*)(smem + 64 * ASTR * 2);

  const int t    = threadIdx.x;
  const int wave = t >> 6;
  const int lane = t & 63;
  const int m    = lane & 15;
  const int quad = lane >> 4;
  const int e0   = blockIdx.x * 64;
  const int wn   = wave * 64;      // this wave's N-base in layer 1

  // ---- staging identity: thread t owns row r=t/4, col-phase sub=t%4 ----
  // chunk cc covers global k in [cc*96, cc*96+96); thread loads 6 float4 at
  // cols sub*4 + q*16 (contiguous 64B across the 4 threads of a row).
  const int sr  = t >> 2;
  const int sub = t & 3;
  const float* pL = l_embs + (size_t)edge_i[e0 + sr] * FEAT + sub * 4;
  const float* pC = c_embs + (size_t)edge_j[e0 + sr] * FEAT + sub * 4;
  bf16_t* sdst = Abuf + sr * ASTR + sub * 4;

  f32x4 acc[4][4];
#pragma unroll
  for (int mt = 0; mt < 4; ++mt)
#pragma unroll
    for (int nt = 0; nt < 4; ++nt) acc[mt][nt] = (f32x4){0.f, 0.f, 0.f, 0.f};

  const bf16_t* wb1 = W1T + (size_t)(wn + m) * F2 + quad * 8;

  // ---- prologue: stage chunk 0 ----
  {
    const float* p = pL;  // chunk 0 < 384
    float4 v[6];
#pragma unroll
    for (int q = 0; q < 6; ++q) v[q] = *(const float4*)(p + q * 16);
#pragma unroll
    for (int q = 0; q < 6; ++q) {
      bf16x4 c;
      c[0] = (bf16_t)v[q].x; c[1] = (bf16_t)v[q].y;
      c[2] = (bf16_t)v[q].z; c[3] = (bf16_t)v[q].w;
      *(bf16x4*)(sdst + q * 16) = c;
    }
  }

  // ---- layer 1: C1[64,256] = emb[64,768] @ W1, K-chunks of 96 ----
  for (int cc = 0; cc < 8; ++cc) {
    // prefetch next chunk into registers (latency hides under MFMA)
    float4 vn[6];
    if (cc < 7) {
      const float* p = (cc + 1 < 4) ? (pL + (cc + 1) * 96) : (pC + (cc + 1 - 4) * 96);
#pragma unroll
      for (int q = 0; q < 6; ++q) vn[q] = *(const float4*)(p + q * 16);
    }
    __syncthreads();   // chunk cc's LDS writes visible
#pragma unroll
    for (int s = 0; s < 3; ++s) {
      bf16x8 af[4];
#pragma unroll
      for (int mt = 0; mt < 4; ++mt)
        af[mt] = *(const bf16x8*)(Abuf + (mt * 16 + m) * ASTR + s * 32 + quad * 8);
      const bf16_t* wb = wb1 + cc * 96 + s * 32;
#pragma unroll
      for (int nt = 0; nt < 4; ++nt) {
        bf16x8 b = *(const bf16x8*)(wb + (size_t)nt * 16 * F2);
#pragma unroll
        for (int mt = 0; mt < 4; ++mt)
          acc[mt][nt] = __builtin_amdgcn_mfma_f32_16x16x32_bf16(af[mt], b, acc[mt][nt], 0, 0, 0);
      }
    }
    if (cc < 7) {
      __syncthreads();  // all waves done reading chunk cc
#pragma unroll
      for (int q = 0; q < 6; ++q) {
        bf16x4 c;
        c[0] = (bf16_t)vn[q].x; c[1] = (bf16_t)vn[q].y;
        c[2] = (bf16_t)vn[q].z; c[3] = (bf16_t)vn[q].w;
        *(bf16x4*)(sdst + q * 16) = c;
      }
    }
  }

  // ---- bias + relu + cvt -> h1 (A-layout for layer 2) ----
#pragma unroll
  for (int nt = 0; nt < 4; ++nt) {
    int col = wn + nt * 16 + m;
    float bb = b1[col];
#pragma unroll
    for (int mt = 0; mt < 4; ++mt)
#pragma unroll
      for (int r = 0; r < 4; ++r)
        h1[(mt * 16 + quad * 4 + r) * H1STR + col] =
            (bf16_t)fmaxf(acc[mt][nt][r] + bb, 0.0f);
  }
  __syncthreads();

  // ---- layer 2: each wave takes 16 edges (rows er..er+15) ----
  const int er = wave * 16;
  f32x4 acc2[4];
#pragma unroll
  for (int nt = 0; nt < 4; ++nt) acc2[nt] = (f32x4){0.f, 0.f, 0.f, 0.f};
#pragma unroll
  for (int s2 = 0; s2 < 8; ++s2) {
    bf16x8 a2 = *(const bf16x8*)(h1 + (er + m) * H1STR + s2 * 32 + quad * 8);
#pragma unroll
    for (int nt = 0; nt < 4; ++nt) {
      bf16x8 b = *(const bf16x8*)(W2T + (size_t)(nt * 16 + m) * H1 + s2 * 32 + quad * 8);
      acc2[nt] = __builtin_amdgcn_mfma_f32_16x16x32_bf16(a2, b, acc2[nt], 0, 0, 0);
    }
  }
  // h2s overlaps Abuf: safe, all Abuf reads completed before the sync above.
#pragma unroll
  for (int nt = 0; nt < 4; ++nt) {
    float bb = b2[nt * 16 + m];
#pragma unroll
    for (int r = 0; r < 4; ++r)
      h2s[(er + quad * 4 + r) * H2STR + nt * 16 + m] =
          (bf16_t)fmaxf(acc2[nt][r] + bb, 0.0f);
  }
  // rows er..er+15 are written and read only by this wave: no barrier needed.

  // ---- layer 3: C3[16,32] = h2[16,64] @ W3pad ----
  f32x4 acc3[2];
#pragma unroll
  for (int nt = 0; nt < 2; ++nt) acc3[nt] = (f32x4){0.f, 0.f, 0.f, 0.f};
#pragma unroll
  for (int s3 = 0; s3 < 2; ++s3) {
    bf16x8 a3 = *(const bf16x8*)(h2s + (er + m) * H2STR + s3 * 32 + quad * 8);
#pragma unroll
    for (int nt = 0; nt < 2; ++nt) {
      bf16x8 b = *(const bf16x8*)(W3T + (size_t)(nt * 16 + m) * H2 + s3 * 32 + quad * 8);
      acc3[nt] = __builtin_amdgcn_mfma_f32_16x16x32_bf16(a3, b, acc3[nt], 0, 0, 0);
    }
  }

  // ---- layer 4 + per-clause atomics ----
  float b3A = b3[m];
  float b3B = (m + 16 < 20) ? b3[m + 16] : 0.0f;
  float w4A = W4[m];
  float w4B = (m + 16 < 20) ? W4[m + 16] : 0.0f;

  float p[4];
#pragma unroll
  for (int r = 0; r < 4; ++r) {
    float hA = fmaxf(acc3[0][r] + b3A, 0.0f);
    float hB = fmaxf(acc3[1][r] + b3B, 0.0f);
    p[r] = hA * w4A + hB * w4B;
  }
#pragma unroll
  for (int d = 1; d < 16; d <<= 1) {
#pragma unroll
    for (int r = 0; r < 4; ++r) p[r] += __shfl_xor(p[r], d, 64);
  }

  if (m == 0) {
    float bb4 = b4[0];
#pragma unroll
    for (int r = 0; r < 4; ++r) {
      int row = er + quad * 4 + r;
      int ej = edge_j[e0 + row];
      atomicAdd(&sums[ej], p[r] + bb4);
      atomicAdd(&counts[ej], 1.0f);
    }
  }
}

// out[e] = sums[edge_j[e]] / max(counts[edge_j[e]], 1)  (mean fused into gather)
__global__ void k_gather(const float* __restrict__ sums, const float* __restrict__ counts,
                         const int* __restrict__ edge_j, float* __restrict__ out) {
  int e = blockIdx.x * blockDim.x + threadIdx.x;
  if (e >= N_EDGES) return;
  int ej = edge_j[e];
  out[e] = sums[ej] / fmaxf(counts[ej], 1.0f);
}

extern "C" void kernel_launch(void* const* d_in, const int* in_sizes, int n_in,
                              void* d_out, int out_size, void* d_ws, size_t ws_size,
                              hipStream_t stream) {
  const float* l_embs = (const float*)d_in[0];
  const float* c_embs = (const float*)d_in[1];
  const int*   edge_i = (const int*)d_in[2];
  const int*   edge_j = (const int*)d_in[3];
  const float* W1 = (const float*)d_in[4];
  const float* b1 = (const float*)d_in[5];
  const float* W2 = (const float*)d_in[6];
  const float* b2 = (const float*)d_in[7];
  const float* W3 = (const float*)d_in[8];
  const float* b3 = (const float*)d_in[9];
  const float* W4 = (const float*)d_in[10];
  const float* b4 = (const float*)d_in[11];
  float* out = (float*)d_out;

  char* ws = (char*)d_ws;
  bf16_t* W1T = (bf16_t*)(ws + OFF_W1T);
  bf16_t* W2T = (bf16_t*)(ws + OFF_W2T);
  bf16_t* W3T = (bf16_t*)(ws + OFF_W3T);
  float*  sums   = (float*)(ws + OFF_SUMS);
  float*  counts = (float*)(ws + OFF_CNTS);

  hipMemsetAsync(ws + OFF_SUMS, 0, 2 * N_CLAUSES * 4, stream);

  k_prep<<<840, 256, 0, stream>>>(W1, W2, W3, W1T, W2T, W3T);

  k_edge_mlp<<<N_EDGES / 64, 256, 0, stream>>>(
      l_embs, c_embs, edge_i, edge_j, W1T, W2T, W3T,
      b1, b2, b3, W4, b4, sums, counts);

  k_gather<<<N_EDGES / 256, 256, 0, stream>>>(sums, counts, edge_j, out);
}